// Round 1
// baseline (335.353 us; speedup 1.0000x reference)
//
#include <hip/hip_runtime.h>

// FastAttention (Performer linear attention), MI355X gfx950.
// B=4 L=4096 H=16 D=E=64 M=256, all fp32 in/out. bf16 MFMA internally.
//
// Pipeline:
//   hipMemsetAsync(ws KV/Ksum region, 0)
//   k1_kv : KVt[bh][e][m] += sum_l phi(k)[l,m]*v[l,e] ; Ksum[bh][m] (fp32 atomics)
//   k3_out: out[l,e] = (phi(q)[l,:] @ KV) / (phi(q)[l,:] . (Ksum+1e-6))
// phi(x) = relu((x*D^-0.25) @ P^T) + 1e-3 ; scale folded into P bf16 conversion.

#define LL 4096
#define HH 16
#define DD 64
#define EE 64
#define MM 256
#define SCALE 0.35355339059327378f  // 64^-0.25

typedef __attribute__((ext_vector_type(8))) __bf16 bf8v;
typedef __attribute__((ext_vector_type(4))) __bf16 bf4v;
typedef __attribute__((ext_vector_type(4))) float f4v;

__device__ __forceinline__ __bf16 f2bf(float f) {
  // round-to-nearest-even fp32 -> bf16 (no NaN handling needed; inputs are normal)
  union { float f; unsigned u; } x; x.f = f;
  unsigned r = (x.u + 0x7FFFu + ((x.u >> 16) & 1u)) >> 16;
  union { unsigned short s; __bf16 b; } y; y.s = (unsigned short)r;
  return y.b;
}

#define MFMA16(a, b, c) __builtin_amdgcn_mfma_f32_16x16x32_bf16(a, b, c, 0, 0, 0)

// ws layout (float elements): [ KVt: 64 bh * 64 e * 256 m ][ Ksum: 64 bh * 256 m ]
#define KV_ELEMS (64 * 64 * 256)
#define KSUM_OFF KV_ELEMS
#define WS_ZERO_BYTES ((size_t)(KV_ELEMS + 64 * 256) * 4)

// ---------------------------------------------------------------------------
// Kernel 1: build KV and Ksum.
// grid (8 chunks, 64 bh), 256 threads. Each block: 512 rows, 8 iters of 64.
// Per wave: owns m-band [64*wave, 64*wave+64).
// ---------------------------------------------------------------------------
__global__ __launch_bounds__(256, 2)
void k1_kv(const float* __restrict__ kin, const float* __restrict__ vin,
           const float* __restrict__ pin, float* __restrict__ ws) {
  __shared__ __bf16 kt[64 * 72];    // k tile, natural [l][d], stride 72 (b128-aligned, bank-even)
  __shared__ __bf16 vt[64 * 68];    // v tile, natural [l][e], stride 68 (b64-aligned, scalar reads ~2-way)
  __shared__ __bf16 kft[256 * 72];  // phi(k)^T [m][l], stride 72

  const int tid = threadIdx.x;
  const int wave = tid >> 6;
  const int lane = tid & 63;
  const int qd = lane >> 4;   // quad
  const int nn = lane & 15;
  const int bh = blockIdx.y;
  const int b = bh >> 4, h = bh & 15;
  const int l0 = blockIdx.x * 512;

  // Preload P fragments (B-operand of GEMM1; also row-indexed by lane&15).
  // pf[mt][c]: rows m = 64*wave + mt*16 + nn, k d = c*32 + qd*8 + j. Scale folded.
  bf8v pf[4][2];
#pragma unroll
  for (int mt = 0; mt < 4; ++mt) {
    const float* pr = pin + (size_t)(64 * wave + mt * 16 + nn) * DD;
#pragma unroll
    for (int c = 0; c < 2; ++c) {
      bf8v t;
#pragma unroll
      for (int j = 0; j < 8; ++j) t[j] = f2bf(pr[c * 32 + qd * 8 + j] * SCALE);
      pf[mt][c] = t;
    }
  }

  f4v acc[4][4];  // KV accum: [mt][et], C rows m = 64w+mt*16+4qd+r, cols e = et*16+nn
#pragma unroll
  for (int i = 0; i < 4; ++i)
#pragma unroll
    for (int j = 0; j < 4; ++j) acc[i][j] = (f4v){0.f, 0.f, 0.f, 0.f};
  float ksum[4] = {0.f, 0.f, 0.f, 0.f};  // per-lane partial for m = 64w+mt*16+nn

  const size_t bhbase = (size_t)b * LL * HH * DD + (size_t)h * DD;
  const int srow = tid >> 2;        // 0..63
  const int scol = (tid & 3) * 16;  // 0,16,32,48

  for (int it = 0; it < 8; ++it) {
    // ---- stage k & v tiles (64 rows x 64 cols each) ----
    {
      const size_t g = bhbase + (size_t)(l0 + it * 64 + srow) * (HH * DD) + scol;
      const f4v* gk = (const f4v*)(kin + g);
      const f4v* gv = (const f4v*)(vin + g);
      f4v k0 = gk[0], k1 = gk[1], k2 = gk[2], k3 = gk[3];
      f4v v0 = gv[0], v1 = gv[1], v2 = gv[2], v3 = gv[3];
      bf8v w0, w1;
#pragma unroll
      for (int j = 0; j < 4; ++j) {
        w0[j] = f2bf(k0[j]); w0[j + 4] = f2bf(k1[j]);
        w1[j] = f2bf(k2[j]); w1[j + 4] = f2bf(k3[j]);
      }
      *(bf8v*)&kt[srow * 72 + scol] = w0;
      *(bf8v*)&kt[srow * 72 + scol + 8] = w1;
      bf4v x0, x1, x2, x3;
#pragma unroll
      for (int j = 0; j < 4; ++j) {
        x0[j] = f2bf(v0[j]); x1[j] = f2bf(v1[j]);
        x2[j] = f2bf(v2[j]); x3[j] = f2bf(v3[j]);
      }
      *(bf4v*)&vt[srow * 68 + scol] = x0;
      *(bf4v*)&vt[srow * 68 + scol + 4] = x1;
      *(bf4v*)&vt[srow * 68 + scol + 8] = x2;
      *(bf4v*)&vt[srow * 68 + scol + 12] = x3;
    }
    __syncthreads();

    // ---- GEMM1: C[l][m] = kt . P^T ; phi ; ksum ; write kft[m][l] (b64 = free transpose) ----
#pragma unroll
    for (int lt = 0; lt < 4; ++lt) {
      bf8v a0 = *(const bf8v*)&kt[(lt * 16 + nn) * 72 + qd * 8];
      bf8v a1 = *(const bf8v*)&kt[(lt * 16 + nn) * 72 + 32 + qd * 8];
#pragma unroll
      for (int mt = 0; mt < 4; ++mt) {
        f4v cc = (f4v){0.f, 0.f, 0.f, 0.f};
        cc = MFMA16(a0, pf[mt][0], cc);
        cc = MFMA16(a1, pf[mt][1], cc);
        // lane holds rows l = lt*16+4qd+r, col m = 64w+mt*16+nn
        bf4v pk;
#pragma unroll
        for (int r = 0; r < 4; ++r) {
          float ph = fmaxf(cc[r], 0.f) + 1e-3f;
          ksum[mt] += ph;  // fp32, pre-rounding
          pk[r] = f2bf(ph);
        }
        *(bf4v*)&kft[(64 * wave + mt * 16 + nn) * 72 + lt * 16 + qd * 4] = pk;
      }
    }

    // ---- GEMM2: acc[m][e] += kft(own band) . v  (same-wave kft RAW: lgkmcnt handled) ----
#pragma unroll
    for (int c = 0; c < 2; ++c) {
      bf8v af[4];
#pragma unroll
      for (int mt = 0; mt < 4; ++mt)
        af[mt] = *(const bf8v*)&kft[(64 * wave + mt * 16 + nn) * 72 + c * 32 + qd * 8];
#pragma unroll
      for (int et = 0; et < 4; ++et) {
        bf8v bv;  // B[k=l][n=e]: column of vt (8 scalar reads; known round-1 cost)
#pragma unroll
        for (int j = 0; j < 8; ++j) bv[j] = vt[(c * 32 + qd * 8 + j) * 68 + et * 16 + nn];
#pragma unroll
        for (int mt = 0; mt < 4; ++mt) acc[mt][et] = MFMA16(af[mt], bv, acc[mt][et]);
      }
    }
    __syncthreads();
  }

  // ---- epilogue: atomic-accumulate KVt[bh][e][m] and Ksum[bh][m] ----
  float* kvb = ws + (size_t)bh * (64 * 256);
#pragma unroll
  for (int mt = 0; mt < 4; ++mt)
#pragma unroll
    for (int et = 0; et < 4; ++et) {
#pragma unroll
      for (int r = 0; r < 4; ++r) {
        int m = 64 * wave + mt * 16 + 4 * qd + r;
        int e = et * 16 + nn;
        atomicAdd(&kvb[e * 256 + m], acc[mt][et][r]);
      }
    }
#pragma unroll
  for (int mt = 0; mt < 4; ++mt) {
    float s = ksum[mt];
    s += __shfl_xor(s, 16, 64);
    s += __shfl_xor(s, 32, 64);
    if (lane < 16) atomicAdd(&ws[KSUM_OFF + bh * 256 + 64 * wave + mt * 16 + lane], s);
  }
}

// ---------------------------------------------------------------------------
// Kernel 3: out = (phi(q) @ KV) / (phi(q) . (Ksum+1e-6)).
// grid (8, 64), 256 threads, 8 iters of 64 rows. KV fragments live in registers
// (wave owns e-band [16*wave,16*wave+16)); P fragments in registers.
// ---------------------------------------------------------------------------
__global__ __launch_bounds__(256, 2)
void k3_out(const float* __restrict__ qin, const float* __restrict__ pin,
            const float* __restrict__ ws, float* __restrict__ out) {
  __shared__ __bf16 qt[64 * 72];    // q tile natural [l][d]
  __shared__ __bf16 qf[64 * 264];   // phi(q) [l][m], stride 264 (bank-even, b128-aligned)
  __shared__ float denp[256];       // per-wave den partials [wave][l]
  __shared__ float denr[64];        // 1/den per l
  __shared__ float ksume[256];      // Ksum + 1e-6 (fp32)

  const int tid = threadIdx.x;
  const int wave = tid >> 6;
  const int lane = tid & 63;
  const int qd = lane >> 4;
  const int nn = lane & 15;
  const int bh = blockIdx.y;
  const int b = bh >> 4, h = bh & 15;
  const int l0 = blockIdx.x * 512;

  // P fragments (A-operand of GEMM3': rows m = 64w+mt*16+nn) — same layout as k1.
  bf8v pf[4][2];
#pragma unroll
  for (int mt = 0; mt < 4; ++mt) {
    const float* pr = pin + (size_t)(64 * wave + mt * 16 + nn) * DD;
#pragma unroll
    for (int c = 0; c < 2; ++c) {
      bf8v t;
#pragma unroll
      for (int j = 0; j < 8; ++j) t[j] = f2bf(pr[c * 32 + qd * 8 + j] * SCALE);
      pf[mt][c] = t;
    }
  }

  // KV fragments: B[k=m][n=e], e = 16*wave + nn, m = c*32 + qd*8 + j.
  const float* kvb = ws + (size_t)bh * (64 * 256);
  bf8v kvf[8];
#pragma unroll
  for (int c = 0; c < 8; ++c) {
    const float* src = kvb + (size_t)(16 * wave + nn) * 256 + c * 32 + qd * 8;
    bf8v t;
#pragma unroll
    for (int j = 0; j < 8; ++j) t[j] = f2bf(src[j]);
    kvf[c] = t;
  }

  ksume[tid] = ws[KSUM_OFF + bh * 256 + tid] + 1e-6f;  // Z_EPS added to Ksum per reference

  const size_t bhbase = (size_t)b * LL * HH * DD + (size_t)h * DD;
  const int srow = tid >> 2;
  const int scol = (tid & 3) * 16;

  for (int it = 0; it < 8; ++it) {
    // ---- stage q tile ----
    {
      const f4v* gq = (const f4v*)(qin + bhbase + (size_t)(l0 + it * 64 + srow) * (HH * DD) + scol);
      f4v q0 = gq[0], q1 = gq[1], q2 = gq[2], q3 = gq[3];
      bf8v w0, w1;
#pragma unroll
      for (int j = 0; j < 4; ++j) {
        w0[j] = f2bf(q0[j]); w0[j + 4] = f2bf(q1[j]);
        w1[j] = f2bf(q2[j]); w1[j + 4] = f2bf(q3[j]);
      }
      *(bf8v*)&qt[srow * 72 + scol] = w0;
      *(bf8v*)&qt[srow * 72 + scol + 8] = w1;
    }
    __syncthreads();  // also covers ksume/kvf first use

    // ---- GEMM3': C[m][l] = P . q^T ; phi ; den partial (fp32) ; write qf[l][m] (b64) ----
#pragma unroll
    for (int lt = 0; lt < 4; ++lt) {
      bf8v b0 = *(const bf8v*)&qt[(lt * 16 + nn) * 72 + qd * 8];
      bf8v b1 = *(const bf8v*)&qt[(lt * 16 + nn) * 72 + 32 + qd * 8];
      float dpart = 0.f;  // lane's col l = lt*16+nn
#pragma unroll
      for (int mt = 0; mt < 4; ++mt) {
        f4v cc = (f4v){0.f, 0.f, 0.f, 0.f};
        cc = MFMA16(pf[mt][0], b0, cc);
        cc = MFMA16(pf[mt][1], b1, cc);
        // lane holds rows m = 64w+mt*16+4qd+r, col l = lt*16+nn
        bf4v pk;
#pragma unroll
        for (int r = 0; r < 4; ++r) {
          float ph = fmaxf(cc[r], 0.f) + 1e-3f;
          dpart += ph * ksume[64 * wave + mt * 16 + 4 * qd + r];
          pk[r] = f2bf(ph);
        }
        *(bf4v*)&qf[(lt * 16 + nn) * 264 + 64 * wave + mt * 16 + 4 * qd] = pk;
      }
      dpart += __shfl_xor(dpart, 16, 64);
      dpart += __shfl_xor(dpart, 32, 64);
      if (lane < 16) denp[wave * 64 + lt * 16 + lane] = dpart;
    }
    __syncthreads();
    if (tid < 64)
      denr[tid] = 1.f / (denp[tid] + denp[64 + tid] + denp[128 + tid] + denp[192 + tid]);
    __syncthreads();

    // ---- GEMM4: out[l][e] = qf . KV, scale by 1/den, store ----
#pragma unroll
    for (int lt = 0; lt < 4; ++lt) {
      f4v co = (f4v){0.f, 0.f, 0.f, 0.f};
#pragma unroll
      for (int c = 0; c < 8; ++c) {
        bf8v af = *(const bf8v*)&qf[(lt * 16 + nn) * 264 + c * 32 + qd * 8];
        co = MFMA16(af, kvf[c], co);
      }
#pragma unroll
      for (int r = 0; r < 4; ++r) {
        int lrel = lt * 16 + 4 * qd + r;
        int labs = l0 + it * 64 + lrel;
        out[((size_t)((size_t)b * LL + labs) * HH + h) * EE + 16 * wave + nn] =
            co[r] * denr[lrel];
      }
    }
    __syncthreads();
  }
}

extern "C" void kernel_launch(void* const* d_in, const int* in_sizes, int n_in,
                              void* d_out, int out_size, void* d_ws, size_t ws_size,
                              hipStream_t stream) {
  (void)in_sizes; (void)n_in; (void)out_size;
  const float* q = (const float*)d_in[0];
  const float* k = (const float*)d_in[1];
  const float* v = (const float*)d_in[2];
  const float* p = (const float*)d_in[3];
  float* ws = (float*)d_ws;
  float* out = (float*)d_out;

  if (ws_size < WS_ZERO_BYTES) return;  // need ~4.3 MB scratch for KV/Ksum

  hipMemsetAsync(d_ws, 0, WS_ZERO_BYTES, stream);
  dim3 grid(8, 64), blk(256);
  k1_kv<<<grid, blk, 0, stream>>>(k, v, p, ws);
  k3_out<<<grid, blk, 0, stream>>>(q, p, ws, out);
}